// Round 1
// baseline (114.583 us; speedup 1.0000x reference)
//
#include <hip/hip_runtime.h>
#include <hip/hip_bf16.h>

// VQ-VAE codebook: z [32,64,32,32] f32 NCHW, embedding [1024,64] f32.
// Outputs (concat, f32): z_q NCHW (2097152) | indices as float (32768) | loss (1).
// N = 32768 rows (n = b*1024 + h*32 + w), D = 64, K = 1024.
// argmin_k ||z_n - e_k||^2  ==  argmin_k ( ||e_k||^2 - 2 z_n.e_k )   (||z||^2 const/row)

#define NROWS 32768
#define DD 64
#define KK 1024
#define ZQ_ELEMS 2097152   // 32*64*32*32
#define IDX_OFF 2097152
#define LOSS_OFF 2129920

// ---------------- kernel A: enorm[k] = sum_d e[k][d]^2 ; zero loss accum ----
__global__ __launch_bounds__(256) void vq_enorm(const float* __restrict__ e,
                                                float* __restrict__ ws) {
    int tid  = threadIdx.x;
    int lane = tid & 63;
    int w    = tid >> 6;
    int k    = blockIdx.x * 4 + w;          // grid = 256 -> k in [0,1024)
    float v  = e[k * DD + lane];
    float s  = v * v;
#pragma unroll
    for (int o = 32; o; o >>= 1) s += __shfl_xor(s, o, 64);
    if (lane == 0) ws[k] = s;
    if (blockIdx.x == 0 && tid == 0) ws[KK] = 0.0f;   // loss accumulator
}

// ---------------- kernel B: main — distances, argmin, z_q, loss ------------
// block = 256 threads (4 waves); block handles 64 rows (lane = row).
// wave w scans k in [w*256, (w+1)*256): e-row is wave-uniform -> SGPR loads.
__global__ __launch_bounds__(256) void vq_main(const float* __restrict__ z,
                                               const float* __restrict__ e,
                                               const float* __restrict__ enorm,
                                               float* __restrict__ loss_acc,
                                               float* __restrict__ out_zq,
                                               float* __restrict__ out_idx) {
    int tid  = threadIdx.x;
    int lane = tid & 63;
    int w    = __builtin_amdgcn_readfirstlane(tid >> 6);  // force wave-uniform
    int n0   = blockIdx.x * 64;                // rows n0..n0+63
    int b    = n0 >> 10;                       // n0 / 1024
    int hw0  = n0 & 1023;

    const float* zbase = z + (size_t)b * 65536 + hw0 + lane;

    // each lane: its z row into 64 VGPRs (coalesced: lane stride 1 in hw)
    float zr[DD];
#pragma unroll
    for (int d = 0; d < DD; ++d) zr[d] = zbase[d * 1024];

    int k0 = w * 256;
    const float* equarter = e + (size_t)k0 * DD;

    float best = 3.4e38f;
    int   bidx = k0;
    for (int k = 0; k < 256; ++k) {
        const float* ek = equarter + k * DD;   // wave-uniform -> s_load
        float d0 = 0.f, d1 = 0.f, d2 = 0.f, d3 = 0.f;
#pragma unroll
        for (int d = 0; d < DD; d += 4) {
            d0 = fmaf(zr[d + 0], ek[d + 0], d0);
            d1 = fmaf(zr[d + 1], ek[d + 1], d1);
            d2 = fmaf(zr[d + 2], ek[d + 2], d2);
            d3 = fmaf(zr[d + 3], ek[d + 3], d3);
        }
        float dot  = (d0 + d1) + (d2 + d3);
        float cand = fmaf(-2.0f, dot, enorm[k0 + k]);  // ||e||^2 - 2 z.e
        if (cand < best) { best = cand; bidx = k0 + k; }  // strict <: first-min
    }

    __shared__ float bv[4][64];
    __shared__ int   bk[4][64];
    __shared__ int   fk[64];
    bv[w][lane] = best;
    bk[w][lane] = bidx;
    __syncthreads();

    if (tid < 64) {
        float v  = bv[0][tid];
        int   ix = bk[0][tid];
#pragma unroll
        for (int ww = 1; ww < 4; ++ww) {
            float v2 = bv[ww][tid];
            if (v2 < v) { v = v2; ix = bk[ww][tid]; }  // ties -> smaller k (earlier wave)
        }
        fk[tid] = ix;
        out_idx[n0 + tid] = (float)ix;
    }
    __syncthreads();

    // epilogue: z_q (coalesced along hw) + loss contribution
    int myk = fk[lane];
    float lsum = 0.f;
#pragma unroll
    for (int i = 0; i < 16; ++i) {
        int d = i * 4 + w;                         // block covers all d in 0..63
        float ev = e[myk * DD + d];                // gather, L2-resident (256 KB)
        float zv = zbase[d * 1024];
        float df = ev - zv;
        lsum = fmaf(df, df, lsum);
        out_zq[(size_t)b * 65536 + d * 1024 + hw0 + lane] = ev;
    }
#pragma unroll
    for (int o = 32; o; o >>= 1) lsum += __shfl_xor(lsum, o, 64);
    if (lane == 0) atomicAdd(loss_acc, lsum);
}

// ---------------- kernel C: finalize loss ---------------------------------
__global__ void vq_finish(const float* __restrict__ ws, float* __restrict__ out_loss) {
    // loss = q_latent + 0.25*e_latent = 1.25 * mean((z_q - z)^2) over 2097152 elems
    out_loss[0] = ws[KK] * (1.25f / 2097152.0f);
}

extern "C" void kernel_launch(void* const* d_in, const int* in_sizes, int n_in,
                              void* d_out, int out_size, void* d_ws, size_t ws_size,
                              hipStream_t stream) {
    const float* z = (const float*)d_in[0];
    const float* e = (const float*)d_in[1];
    float* out = (float*)d_out;
    float* ws  = (float*)d_ws;

    vq_enorm<<<256, 256, 0, stream>>>(e, ws);
    vq_main<<<512, 256, 0, stream>>>(z, e, ws, ws + KK, out, out + IDX_OFF);
    vq_finish<<<1, 1, 0, stream>>>(ws, out + LOSS_OFF);
}

// Round 2
// 113.725 us; speedup vs baseline: 1.0075x; 1.0075x over previous
//
#include <hip/hip_runtime.h>
#include <hip/hip_bf16.h>

// VQ-VAE codebook: z [32,64,32,32] f32 NCHW, embedding [1024,64] f32.
// Outputs (concat, f32): z_q NCHW (2097152) | indices as float (32768) | loss (1).
// N = 32768 rows (n = b*1024 + h*32 + w), D = 64, K = 1024.
// argmin_k ||z_n - e_k||^2  ==  argmin_k ( ||e_k||^2 - 2 z_n.e_k )   (||z||^2 const/row)

#define NROWS 32768
#define DD 64
#define KK 1024
#define IDX_OFF 2097152
#define LOSS_OFF 2129920

// ---------------- kernel A: enorm[k] = sum_d e[k][d]^2 ; zero loss accum ----
__global__ __launch_bounds__(256) void vq_enorm(const float* __restrict__ e,
                                                float* __restrict__ ws) {
    int tid  = threadIdx.x;
    int lane = tid & 63;
    int w    = tid >> 6;
    int k    = blockIdx.x * 4 + w;          // grid = 256 -> k in [0,1024)
    float v  = e[k * DD + lane];
    float s  = v * v;
#pragma unroll
    for (int o = 32; o; o >>= 1) s += __shfl_xor(s, o, 64);
    if (lane == 0) ws[k] = s;
    if (blockIdx.x == 0 && tid == 0) ws[KK] = 0.0f;   // loss accumulator
}

// ---------------- kernel B: main — distances, argmin, z_q, loss ------------
// block = 512 threads (8 waves); block handles 64 rows (lane = row).
// wave w scans k in [w*128, (w+1)*128): e-row is wave-uniform -> SGPR loads.
// __launch_bounds__(512, 4): cap 128 VGPR/thread so zr[64] stays resident.
__global__ __launch_bounds__(512, 4) void vq_main(const float* __restrict__ z,
                                                  const float* __restrict__ e,
                                                  const float* __restrict__ enorm,
                                                  float* __restrict__ loss_acc,
                                                  float* __restrict__ out_zq,
                                                  float* __restrict__ out_idx) {
    int tid  = threadIdx.x;
    int lane = tid & 63;
    int w    = __builtin_amdgcn_readfirstlane(tid >> 6);  // 0..7, wave-uniform
    int n0   = blockIdx.x * 64;                // rows n0..n0+63
    int b    = n0 >> 10;                       // n0 / 1024
    int hw0  = n0 & 1023;

    const float* zbase = z + (size_t)b * 65536 + hw0 + lane;

    // each lane: its z row into 64 VGPRs (coalesced: lane stride 1 in hw)
    float zr[DD];
#pragma unroll
    for (int d = 0; d < DD; ++d) zr[d] = zbase[d * 1024];

    int k0 = w * 128;
    const float* epart = e + (size_t)k0 * DD;

    float best = 3.4e38f;
    int   bidx = k0;
    for (int k = 0; k < 128; ++k) {
        const float* ek = epart + k * DD;      // wave-uniform -> s_load
        float d0 = 0.f, d1 = 0.f, d2 = 0.f, d3 = 0.f;
#pragma unroll
        for (int d = 0; d < DD; d += 4) {
            d0 = fmaf(zr[d + 0], ek[d + 0], d0);
            d1 = fmaf(zr[d + 1], ek[d + 1], d1);
            d2 = fmaf(zr[d + 2], ek[d + 2], d2);
            d3 = fmaf(zr[d + 3], ek[d + 3], d3);
        }
        float dot  = (d0 + d1) + (d2 + d3);
        float cand = fmaf(-2.0f, dot, enorm[k0 + k]);  // ||e||^2 - 2 z.e
        if (cand < best) { best = cand; bidx = k0 + k; }  // strict <: first-min
    }

    __shared__ float bv[8][64];
    __shared__ int   bk[8][64];
    __shared__ int   fk[64];
    bv[w][lane] = best;
    bk[w][lane] = bidx;
    __syncthreads();

    if (tid < 64) {
        float v  = bv[0][tid];
        int   ix = bk[0][tid];
#pragma unroll
        for (int ww = 1; ww < 8; ++ww) {
            float v2 = bv[ww][tid];
            if (v2 < v) { v = v2; ix = bk[ww][tid]; }  // ties -> smaller k (earlier wave)
        }
        fk[tid] = ix;
        out_idx[n0 + tid] = (float)ix;
    }
    __syncthreads();

    // epilogue: z_q (coalesced along hw) + loss contribution
    int myk = fk[lane];
    float lsum = 0.f;
#pragma unroll
    for (int i = 0; i < 8; ++i) {
        int d = i * 8 + w;                         // 8 waves x 8 iters cover d=0..63
        float ev = e[myk * DD + d];                // gather, L2-resident (256 KB)
        float zv = zbase[d * 1024];
        float df = ev - zv;
        lsum = fmaf(df, df, lsum);
        out_zq[(size_t)b * 65536 + d * 1024 + hw0 + lane] = ev;
    }
#pragma unroll
    for (int o = 32; o; o >>= 1) lsum += __shfl_xor(lsum, o, 64);
    if (lane == 0) atomicAdd(loss_acc, lsum);
}

// ---------------- kernel C: finalize loss ---------------------------------
__global__ void vq_finish(const float* __restrict__ ws, float* __restrict__ out_loss) {
    // loss = q_latent + 0.25*e_latent = 1.25 * mean((z_q - z)^2) over 2097152 elems
    out_loss[0] = ws[KK] * (1.25f / 2097152.0f);
}

extern "C" void kernel_launch(void* const* d_in, const int* in_sizes, int n_in,
                              void* d_out, int out_size, void* d_ws, size_t ws_size,
                              hipStream_t stream) {
    const float* z = (const float*)d_in[0];
    const float* e = (const float*)d_in[1];
    float* out = (float*)d_out;
    float* ws  = (float*)d_ws;

    vq_enorm<<<256, 256, 0, stream>>>(e, ws);
    vq_main<<<512, 512, 0, stream>>>(z, e, ws, ws + KK, out, out + IDX_OFF);
    vq_finish<<<1, 1, 0, stream>>>(ws, out + LOSS_OFF);
}

// Round 3
// 113.108 us; speedup vs baseline: 1.0130x; 1.0055x over previous
//
#include <hip/hip_runtime.h>
#include <hip/hip_bf16.h>

// VQ-VAE codebook: z [32,64,32,32] f32 NCHW, embedding [1024,64] f32.
// Outputs (concat, f32): z_q NCHW (2097152) | indices as float (32768) | loss (1).
// N = 32768 rows (n = b*1024 + h*32 + w), D = 64, K = 1024.
// argmin_k ||z_n - e_k||^2  ==  argmin_k ( ||e_k||^2 - 2 z_n.e_k )   (||z||^2 const/row)

#define NROWS 32768
#define DD 64
#define KK 1024
#define IDX_OFF 2097152
#define LOSS_OFF 2129920

// ---------------- kernel A: enorm[k] = sum_d e[k][d]^2 ; zero loss accum ----
__global__ __launch_bounds__(256) void vq_enorm(const float* __restrict__ e,
                                                float* __restrict__ ws) {
    int tid  = threadIdx.x;
    int lane = tid & 63;
    int w    = tid >> 6;
    int k    = blockIdx.x * 4 + w;          // grid = 256 -> k in [0,1024)
    float v  = e[k * DD + lane];
    float s  = v * v;
#pragma unroll
    for (int o = 32; o; o >>= 1) s += __shfl_xor(s, o, 64);
    if (lane == 0) ws[k] = s;
    if (blockIdx.x == 0 && tid == 0) ws[KK] = 0.0f;   // loss accumulator
}

// ---------------- kernel B: main — distances, argmin, z_q, loss ------------
// block = 512 threads (8 waves); block handles 64 rows (lane = row).
// wave w scans k in [w*128, (w+1)*128): e-row is wave-uniform -> s_load to SGPRs.
// zr[64] is pinned into VGPRs via inline-asm so the scheduler cannot sink the
// z loads into the k-loop (R2 post-mortem: VGPR=40 showed it re-read z from L1
// 128x per row; launch_bounds alone doesn't prevent load sinking).
__global__ __launch_bounds__(512, 4) void vq_main(const float* __restrict__ z,
                                                  const float* __restrict__ e,
                                                  const float* __restrict__ enorm,
                                                  float* __restrict__ loss_acc,
                                                  float* __restrict__ out_zq,
                                                  float* __restrict__ out_idx) {
    int tid  = threadIdx.x;
    int lane = tid & 63;
    int w    = __builtin_amdgcn_readfirstlane(tid >> 6);  // 0..7, wave-uniform
    int n0   = blockIdx.x * 64;                // rows n0..n0+63
    int b    = n0 >> 10;                       // n0 / 1024
    int hw0  = n0 & 1023;

    const float* zbase = z + (size_t)b * 65536 + hw0 + lane;

    // each lane: its z row into 64 VGPRs (coalesced: lane stride 1 in hw)
    float zr[DD];
#pragma unroll
    for (int d = 0; d < DD; ++d) zr[d] = zbase[d * 1024];
    // pin: value now produced by opaque asm -> cannot be rematerialized/sunk
#pragma unroll
    for (int d = 0; d < DD; ++d) asm volatile("" : "+v"(zr[d]));

    int k0 = w * 128;
    const float* epart = e + (size_t)k0 * DD;

    float best = 3.4e38f;
    int   bidx = k0;
    for (int k = 0; k < 128; ++k) {
        const float* ek = epart + k * DD;      // wave-uniform -> s_load
        float d0 = 0.f, d1 = 0.f, d2 = 0.f, d3 = 0.f;
#pragma unroll
        for (int d = 0; d < DD; d += 4) {
            d0 = fmaf(zr[d + 0], ek[d + 0], d0);
            d1 = fmaf(zr[d + 1], ek[d + 1], d1);
            d2 = fmaf(zr[d + 2], ek[d + 2], d2);
            d3 = fmaf(zr[d + 3], ek[d + 3], d3);
        }
        float dot  = (d0 + d1) + (d2 + d3);
        float cand = fmaf(-2.0f, dot, enorm[k0 + k]);  // ||e||^2 - 2 z.e
        if (cand < best) { best = cand; bidx = k0 + k; }  // strict <: first-min
    }

    __shared__ float bv[8][64];
    __shared__ int   bk[8][64];
    __shared__ int   fk[64];
    bv[w][lane] = best;
    bk[w][lane] = bidx;
    __syncthreads();

    if (tid < 64) {
        float v  = bv[0][tid];
        int   ix = bk[0][tid];
#pragma unroll
        for (int ww = 1; ww < 8; ++ww) {
            float v2 = bv[ww][tid];
            if (v2 < v) { v = v2; ix = bk[ww][tid]; }  // ties -> smaller k (earlier wave)
        }
        fk[tid] = ix;
        out_idx[n0 + tid] = (float)ix;
    }
    __syncthreads();

    // epilogue: z_q (coalesced along hw) + loss contribution
    int myk = fk[lane];
    float lsum = 0.f;
#pragma unroll
    for (int i = 0; i < 8; ++i) {
        int d = i * 8 + w;                         // 8 waves x 8 iters cover d=0..63
        float ev = e[myk * DD + d];                // gather, L2-resident (256 KB)
        float zv = zbase[d * 1024];
        float df = ev - zv;
        lsum = fmaf(df, df, lsum);
        out_zq[(size_t)b * 65536 + d * 1024 + hw0 + lane] = ev;
    }
#pragma unroll
    for (int o = 32; o; o >>= 1) lsum += __shfl_xor(lsum, o, 64);
    if (lane == 0) atomicAdd(loss_acc, lsum);
}

// ---------------- kernel C: finalize loss ---------------------------------
__global__ void vq_finish(const float* __restrict__ ws, float* __restrict__ out_loss) {
    // loss = q_latent + 0.25*e_latent = 1.25 * mean((z_q - z)^2) over 2097152 elems
    out_loss[0] = ws[KK] * (1.25f / 2097152.0f);
}

extern "C" void kernel_launch(void* const* d_in, const int* in_sizes, int n_in,
                              void* d_out, int out_size, void* d_ws, size_t ws_size,
                              hipStream_t stream) {
    const float* z = (const float*)d_in[0];
    const float* e = (const float*)d_in[1];
    float* out = (float*)d_out;
    float* ws  = (float*)d_ws;

    vq_enorm<<<256, 256, 0, stream>>>(e, ws);
    vq_main<<<512, 512, 0, stream>>>(z, e, ws, ws + KK, out, out + IDX_OFF);
    vq_finish<<<1, 1, 0, stream>>>(ws, out + LOSS_OFF);
}